// Round 1
// baseline (146.844 us; speedup 1.0000x reference)
//
#include <hip/hip_runtime.h>
#include <hip/hip_bf16.h>

typedef __bf16 bf16x8 __attribute__((ext_vector_type(8)));
typedef __bf16 bf16x4 __attribute__((ext_vector_type(4)));
typedef float  float4v __attribute__((ext_vector_type(4)));

__device__ __forceinline__ float bf2f(unsigned short u){
  union { unsigned int i; float f; } x; x.i = ((unsigned int)u) << 16; return x.f;
}
__device__ __forceinline__ unsigned short f2bf(float f){
  union { float f; unsigned int i; } x; x.f = f;
  unsigned int r = x.i + 0x7FFFu + ((x.i >> 16) & 1u);
  return (unsigned short)(r >> 16);
}
__device__ __forceinline__ float ldin(const void* p, int i, bool isbf){
  return isbf ? bf2f(((const unsigned short*)p)[i]) : ((const float*)p)[i];
}
__device__ __forceinline__ float frcp(float x){ return __builtin_amdgcn_rcpf(x); }

// ---------------- prep kernel ----------------
// ws layout (bytes):
//   0      : meta int[2] {isbf, max_step}
//   256    : at f32[64]
//   512    : b  f32[128]
//   1024   : KmHi bf16[64*64]     (value relu(K)[l][a] at [l][a])
//   9216   : KmLo
//   17408  : KTHi                 (value relu(K)[l][a] at [a][l])
//   25600  : KTLo
//   33792  : ltf f32[4096*64]
//   1082368: W2T bf16[128][4224]  (W2T[y][k]: k<4096 -> Km*u, 4096..4159 -> e, pad 0)
__global__ __launch_bounds__(256) void k_prep(
    const void* LT, const void* K, const void* AT, const void* u,
    const void* e, const void* bvec, const int* msin,
    float* ltf, __bf16* KmHi, __bf16* KmLo, __bf16* KTHi, __bf16* KTLo,
    float* atf, float* bf_, __bf16* W2T, int* meta)
{
  int tid = threadIdx.x, bid = blockIdx.x;
  // dtype detection: read AT as 64 bf16 halfwords; f32 data -> garbage in even slots
  int ok = 0;
  if (tid < 64){
    float v = bf2f(((const unsigned short*)AT)[tid]);
    ok = (v >= 0.f && v <= 1.0f) ? 1 : 0;
  }
  int cnt = __syncthreads_count(ok);
  bool isbf = (cnt >= 60);

  if (bid < 256){
    // W2T u-region: transpose tile k:64 x y:32
    int k0 = (bid >> 2) * 64, y0 = (bid & 3) * 32;
    __shared__ float sT[64 * 33];
    #pragma unroll
    for (int i = 0; i < 8; ++i){
      int flat = i * 256 + tid;
      int r = flat >> 5, c = flat & 31;
      sT[r * 33 + c] = ldin(u, (k0 + r) * 128 + (y0 + c), isbf);
    }
    __syncthreads();
    int l = k0 >> 6;
    #pragma unroll
    for (int i = 0; i < 8; ++i){
      int flat = i * 256 + tid;
      int yl = flat >> 6, kl = flat & 63;
      float km = ldin(K, l * 64 + kl, isbf); km = km > 0.f ? km : 0.f;
      W2T[(y0 + yl) * 4224 + (k0 + kl)] = (__bf16)(km * sT[kl * 33 + yl]);
    }
    // LT -> f32
    #pragma unroll
    for (int i = 0; i < 4; ++i){
      int idx = bid * 1024 + i * 256 + tid;
      ltf[idx] = ldin(LT, idx, isbf);
    }
  } else {
    // Km split arrays
    #pragma unroll
    for (int i = 0; i < 16; ++i){
      int idx = i * 256 + tid;          // 0..4095
      int l = idx >> 6, a = idx & 63;
      float v = ldin(K, idx, isbf); v = v > 0.f ? v : 0.f;
      __bf16 hi = (__bf16)v;
      __bf16 lo = (__bf16)(v - (float)hi);
      KmHi[idx] = hi; KmLo[idx] = lo;
      KTHi[a * 64 + l] = hi; KTLo[a * 64 + l] = lo;
    }
    if (tid < 64){ float v = ldin(AT, tid, isbf); atf[tid] = v > 0.f ? v : 0.f; }
    if (tid < 128){ bf_[tid] = ldin(bvec, tid, isbf); }
    // e-region
    #pragma unroll
    for (int i = 0; i < 32; ++i){
      int idx = i * 256 + tid;          // 0..8191
      int a = idx >> 7, y = idx & 127;
      W2T[y * 4224 + 4096 + a] = (__bf16)ldin(e, a * 128 + y, isbf);
    }
    // pad-region zeros
    #pragma unroll
    for (int i = 0; i < 32; ++i){
      int idx = i * 256 + tid;
      int j = idx >> 7, y = idx & 127;
      W2T[y * 4224 + 4160 + j] = (__bf16)0.f;
    }
    if (tid == 0){
      meta[0] = isbf ? 1 : 0;
      int mi = msin[0];
      if (mi <= 0 || mi > 1000000){
        float mf = ((const float*)msin)[0];
        mi = (mf > 0.f && mf < 1.0e6f) ? (int)mf : 50;
      }
      meta[1] = mi;
    }
  }
}

// split-bf16 GEMM quarter: acc = A(16xK64, invariant frags) @ Bstate(16 rows x 64)
__device__ __forceinline__ float4v gemm3(const bf16x8* aH, const bf16x8* aL,
                                         const __bf16* bHi, const __bf16* bLo,
                                         int boff){
  float4v acc = {0.f, 0.f, 0.f, 0.f};
  #pragma unroll
  for (int ks = 0; ks < 2; ++ks){
    bf16x8 bH = *(const bf16x8*)(bHi + boff + ks * 32);
    bf16x8 bL = *(const bf16x8*)(bLo + boff + ks * 32);
    acc = __builtin_amdgcn_mfma_f32_16x16x32_bf16(aH[ks], bH, acc, 0, 0, 0);
    acc = __builtin_amdgcn_mfma_f32_16x16x32_bf16(aH[ks], bL, acc, 0, 0, 0);
    acc = __builtin_amdgcn_mfma_f32_16x16x32_bf16(aL[ks], bH, acc, 0, 0, 0);
  }
  return acc;
}

// ---------------- main kernel: 16 rows per block, 4 waves ----------------
__global__ __launch_bounds__(256) void k_main(
    const float* ltf, const __bf16* KmHi, const __bf16* KmLo,
    const __bf16* KTHi, const __bf16* KTLo, const float* atf, const float* bf_,
    const __bf16* W2T, const int* meta, void* out)
{
  __shared__ __attribute__((aligned(16))) __bf16 sAFh[16*72], sAFl[16*72];
  __shared__ __attribute__((aligned(16))) __bf16 sLFh[16*72], sLFl[16*72];
  __shared__ __attribute__((aligned(16))) __bf16 sLdh[16*72], sLdl[16*72];
  __shared__ __attribute__((aligned(16))) __bf16 sAdh[16*72], sAdl[16*72];
  __shared__ __attribute__((aligned(16))) __bf16 sD[16*136];
  __shared__ float sErrA[4], sErrL[4];

  const int tid = threadIdx.x;
  const int wave = tid >> 6, lane = tid & 63;
  const int lr = lane & 15, q = lane >> 4;
  const int row0 = blockIdx.x * 16;
  const int dq = wave * 16 + q * 4;      // dim-quad base (l or a) this lane owns
  const int boff = lr * 72 + q * 8;      // B-fragment base offset
  const int woff = lr * 72 + dq;         // C-quad writeback offset

  for (int i = tid; i < 16 * 72; i += 256){
    sAFh[i] = (__bf16)0.f; sAFl[i] = (__bf16)0.f;
    sLFh[i] = (__bf16)0.f; sLFl[i] = (__bf16)0.f;
  }

  // invariant A-fragments (Km orient for G1/G4, KmT orient for G2/G3)
  bf16x8 aKmH[2], aKmL[2], aKTH[2], aKTL[2];
  #pragma unroll
  for (int ks = 0; ks < 2; ++ks){
    int o = (wave * 16 + lr) * 64 + ks * 32 + q * 8;
    aKmH[ks] = *(const bf16x8*)(KmHi + o);
    aKmL[ks] = *(const bf16x8*)(KmLo + o);
    aKTH[ks] = *(const bf16x8*)(KTHi + o);
    aKTL[ks] = *(const bf16x8*)(KTLo + o);
  }
  const float4v ltv = *(const float4v*)(ltf + (row0 + lr) * 64 + dq);
  const float4v atv = *(const float4v*)(atf + dq);
  const int isbf = meta[0];
  const int ms   = meta[1];

  float4v afold = {0.f,0.f,0.f,0.f}, lfold = {0.f,0.f,0.f,0.f};
  __syncthreads();

  for (int step = 0; step < ms; ++step){
    float4v s1 = gemm3(aKmH, aKmL, sAFh, sAFl, boff);   // Km @ AF   (out m=l)
    float4v t2 = gemm3(aKTH, aKTL, sLFh, sLFl, boff);   // KmT @ LF  (out m=a)
    bf16x4 ldh, ldl, adh, adl;
    #pragma unroll
    for (int r = 0; r < 4; ++r){
      float ldi = ltv[r] * frcp(s1[r] + 1.f);
      float adi = atv[r] * frcp(t2[r] + 1.f);
      __bf16 h1 = (__bf16)ldi; ldh[r] = h1; ldl[r] = (__bf16)(ldi - (float)h1);
      __bf16 h2 = (__bf16)adi; adh[r] = h2; adl[r] = (__bf16)(adi - (float)h2);
    }
    *(bf16x4*)(sLdh + woff) = ldh; *(bf16x4*)(sLdl + woff) = ldl;
    *(bf16x4*)(sAdh + woff) = adh; *(bf16x4*)(sAdl + woff) = adl;
    __syncthreads();
    float4v t3 = gemm3(aKTH, aKTL, sLdh, sLdl, boff);   // KmT @ Ldi (out m=a)
    float4v t4 = gemm3(aKmH, aKmL, sAdh, sAdl, boff);   // Km @ Adi  (out m=l)
    float eA = 0.f, eL = 0.f;
    bf16x4 afh, afl, lfh, lfl;
    float4v afnew, lfnew;
    #pragma unroll
    for (int r = 0; r < 4; ++r){
      float afn = atv[r] * frcp(t3[r] + 1.f);
      float lfn = ltv[r] * frcp(t4[r] + 1.f);
      afnew[r] = afn; lfnew[r] = lfn;
      eA = fmaxf(eA, fabsf(afn - afold[r]) * frcp(afold[r] + 1e-5f));
      eL = fmaxf(eL, fabsf(lfn - lfold[r]) * frcp(lfold[r] + 1e-5f));
      __bf16 h1 = (__bf16)afn; afh[r] = h1; afl[r] = (__bf16)(afn - (float)h1);
      __bf16 h2 = (__bf16)lfn; lfh[r] = h2; lfl[r] = (__bf16)(lfn - (float)h2);
    }
    afold = afnew; lfold = lfnew;
    *(bf16x4*)(sAFh + woff) = afh; *(bf16x4*)(sAFl + woff) = afl;
    *(bf16x4*)(sLFh + woff) = lfh; *(bf16x4*)(sLFl + woff) = lfl;
    #pragma unroll
    for (int off = 32; off >= 1; off >>= 1){
      eA = fmaxf(eA, __shfl_xor(eA, off));
      eL = fmaxf(eL, __shfl_xor(eL, off));
    }
    if (lane == 0){ sErrA[wave] = eA; sErrL[wave] = eL; }
    __syncthreads();
    float err = fmaxf(fmaxf(sErrA[0], sErrA[1]), fmaxf(sErrA[2], sErrA[3]))
              + fmaxf(fmaxf(sErrL[0], sErrL[1]), fmaxf(sErrL[2], sErrL[3]));
    if (err < 1e-3f) break;
  }

  // final extra half-step pair -> AFf, LFf (bf16-hi into sAFh/sLFh)
  {
    float4v s1 = gemm3(aKmH, aKmL, sAFh, sAFl, boff);
    float4v t2 = gemm3(aKTH, aKTL, sLFh, sLFl, boff);
    bf16x4 ldh, ldl, adh, adl;
    #pragma unroll
    for (int r = 0; r < 4; ++r){
      float ldi = ltv[r] * frcp(s1[r] + 1.f);
      float adi = atv[r] * frcp(t2[r] + 1.f);
      __bf16 h1 = (__bf16)ldi; ldh[r] = h1; ldl[r] = (__bf16)(ldi - (float)h1);
      __bf16 h2 = (__bf16)adi; adh[r] = h2; adl[r] = (__bf16)(adi - (float)h2);
    }
    *(bf16x4*)(sLdh + woff) = ldh; *(bf16x4*)(sLdl + woff) = ldl;
    *(bf16x4*)(sAdh + woff) = adh; *(bf16x4*)(sAdl + woff) = adl;
    __syncthreads();
    float4v t3 = gemm3(aKTH, aKTL, sLdh, sLdl, boff);
    float4v t4 = gemm3(aKmH, aKmL, sAdh, sAdl, boff);
    bf16x4 afh, lfh;
    #pragma unroll
    for (int r = 0; r < 4; ++r){
      afh[r] = (__bf16)(atv[r] * frcp(t3[r] + 1.f));
      lfh[r] = (__bf16)(ltv[r] * frcp(t4[r] + 1.f));
    }
    *(bf16x4*)(sAFh + woff) = afh; *(bf16x4*)(sLFh + woff) = lfh;
    __syncthreads();
  }

  // epilogue: y[16 x 128] = [D | AFf | 0] (16 x 4224) @ W2T^T + bias
  float4v acc0 = {0.f,0.f,0.f,0.f}, acc1 = {0.f,0.f,0.f,0.f};
  const int nBase = wave * 32;
  const int br  = tid >> 4;          // builder row
  const int bk0 = (tid & 15) * 8;    // builder k-offset in chunk
  for (int kc = 0; kc < 33; ++kc){
    int kg0 = kc * 128 + bk0;
    bf16x8 dv;
    if (kg0 < 4096){
      int l = kg0 >> 6, a0 = kg0 & 63;
      float lf = (float)sLFh[br * 72 + l];
      bf16x8 af = *(const bf16x8*)(sAFh + br * 72 + a0);
      #pragma unroll
      for (int j = 0; j < 8; ++j) dv[j] = (__bf16)(lf * (float)af[j]);
    } else if (kg0 < 4160){
      dv = *(const bf16x8*)(sAFh + br * 72 + (kg0 - 4096));
    } else {
      #pragma unroll
      for (int j = 0; j < 8; ++j) dv[j] = (__bf16)0.f;
    }
    __syncthreads();                       // prior chunk's A-frag reads done
    *(bf16x8*)(sD + br * 136 + bk0) = dv;
    __syncthreads();
    #pragma unroll
    for (int kt = 0; kt < 4; ++kt){
      bf16x8 aD = *(const bf16x8*)(sD + lr * 136 + kt * 32 + q * 8);
      const __bf16* w0 = W2T + (nBase + lr) * 4224 + kc * 128 + kt * 32 + q * 8;
      bf16x8 b0 = *(const bf16x8*)w0;
      bf16x8 b1 = *(const bf16x8*)(w0 + 16 * 4224);
      acc0 = __builtin_amdgcn_mfma_f32_16x16x32_bf16(aD, b0, acc0, 0, 0, 0);
      acc1 = __builtin_amdgcn_mfma_f32_16x16x32_bf16(aD, b1, acc1, 0, 0, 0);
    }
  }

  const float b0v = bf_[nBase + lr];
  const float b1v = bf_[nBase + 16 + lr];
  const int obase = (row0 + q * 4) * 128;
  if (isbf){
    unsigned short* o = (unsigned short*)out;
    #pragma unroll
    for (int r = 0; r < 4; ++r){
      o[obase + r * 128 + nBase + lr]      = f2bf(acc0[r] + b0v);
      o[obase + r * 128 + nBase + 16 + lr] = f2bf(acc1[r] + b1v);
    }
  } else {
    float* o = (float*)out;
    #pragma unroll
    for (int r = 0; r < 4; ++r){
      o[obase + r * 128 + nBase + lr]      = acc0[r] + b0v;
      o[obase + r * 128 + nBase + 16 + lr] = acc1[r] + b1v;
    }
  }
}

extern "C" void kernel_launch(void* const* d_in, const int* in_sizes, int n_in,
                              void* d_out, int out_size, void* d_ws, size_t ws_size,
                              hipStream_t stream){
  char* ws = (char*)d_ws;
  int*    meta = (int*)ws;
  float*  atf  = (float*)(ws + 256);
  float*  bf_  = (float*)(ws + 512);
  __bf16* KmHi = (__bf16*)(ws + 1024);
  __bf16* KmLo = (__bf16*)(ws + 1024 + 8192);
  __bf16* KTHi = (__bf16*)(ws + 1024 + 16384);
  __bf16* KTLo = (__bf16*)(ws + 1024 + 24576);
  float*  ltf  = (float*)(ws + 33792);
  __bf16* W2T  = (__bf16*)(ws + 33792 + 1048576);

  k_prep<<<dim3(257), dim3(256), 0, stream>>>(
      d_in[0], d_in[1], d_in[2], d_in[3], d_in[4], d_in[5], (const int*)d_in[6],
      ltf, KmHi, KmLo, KTHi, KTLo, atf, bf_, W2T, meta);
  k_main<<<dim3(256), dim3(256), 0, stream>>>(
      ltf, KmHi, KmLo, KTHi, KTLo, atf, bf_, W2T, meta, d_out);
}

// Round 2
// 131.793 us; speedup vs baseline: 1.1142x; 1.1142x over previous
//
#include <hip/hip_runtime.h>
#include <hip/hip_bf16.h>

typedef __bf16 bf16x8 __attribute__((ext_vector_type(8)));
typedef __bf16 bf16x4 __attribute__((ext_vector_type(4)));
typedef float  float4v __attribute__((ext_vector_type(4)));

__device__ __forceinline__ float bf2f(unsigned short u){
  union { unsigned int i; float f; } x; x.i = ((unsigned int)u) << 16; return x.f;
}
__device__ __forceinline__ unsigned short f2bf(float f){
  union { float f; unsigned int i; } x; x.f = f;
  unsigned int r = x.i + 0x7FFFu + ((x.i >> 16) & 1u);
  return (unsigned short)(r >> 16);
}
__device__ __forceinline__ float ldin(const void* p, int i, bool isbf){
  return isbf ? bf2f(((const unsigned short*)p)[i]) : ((const float*)p)[i];
}
__device__ __forceinline__ float frcp(float x){ return __builtin_amdgcn_rcpf(x); }

#define SROW 136   // bf16 elems per state row: 8 kblks x (hi8|lo8); 272 B, 16-aligned

// ---------------- prep kernel ----------------
// ws layout (bytes):
//   0      : meta int[2] {isbf, max_step}
//   256    : at f32[64]
//   512    : b  f32[128]
//   1024   : KmHi bf16[64*64]     (relu(K)[l][a] at [l][a])
//   9216   : KmLo
//   17408  : KTHi                 (relu(K)[l][a] at [a][l])
//   25600  : KTLo
//   33792  : ltf f32[4096*64]
//   1082368: W2T bf16[128][4224]  (k<4096 -> Km*u ; 4096..4159 -> e ; 4160+ never read)
__global__ __launch_bounds__(256) void k_prep(
    const void* LT, const void* K, const void* AT, const void* u,
    const void* e, const void* bvec, const int* msin,
    float* ltf, __bf16* KmHi, __bf16* KmLo, __bf16* KTHi, __bf16* KTLo,
    float* atf, float* bf_, __bf16* W2T, int* meta)
{
  int tid = threadIdx.x, bid = blockIdx.x;
  // dtype detection: read AT as 64 bf16 halfwords; f32 data -> garbage values
  int ok = 0;
  if (tid < 64){
    float v = bf2f(((const unsigned short*)AT)[tid]);
    ok = (v >= 0.f && v <= 1.0f) ? 1 : 0;
  }
  int cnt = __syncthreads_count(ok);
  bool isbf = (cnt >= 60);

  if (bid < 256){
    // W2T u-region: transpose tile k:64 x y:32
    int k0 = (bid >> 2) * 64, y0 = (bid & 3) * 32;
    __shared__ float sT[64 * 33];
    #pragma unroll
    for (int i = 0; i < 8; ++i){
      int flat = i * 256 + tid;
      int r = flat >> 5, c = flat & 31;
      sT[r * 33 + c] = ldin(u, (k0 + r) * 128 + (y0 + c), isbf);
    }
    __syncthreads();
    int l = k0 >> 6;
    #pragma unroll
    for (int i = 0; i < 8; ++i){
      int flat = i * 256 + tid;
      int yl = flat >> 6, kl = flat & 63;
      float km = ldin(K, l * 64 + kl, isbf); km = km > 0.f ? km : 0.f;
      W2T[(y0 + yl) * 4224 + (k0 + kl)] = (__bf16)(km * sT[kl * 33 + yl]);
    }
    // LT -> f32
    #pragma unroll
    for (int i = 0; i < 4; ++i){
      int idx = bid * 1024 + i * 256 + tid;
      ltf[idx] = ldin(LT, idx, isbf);
    }
  } else {
    // Km split arrays
    #pragma unroll
    for (int i = 0; i < 16; ++i){
      int idx = i * 256 + tid;          // 0..4095
      int l = idx >> 6, a = idx & 63;
      float v = ldin(K, idx, isbf); v = v > 0.f ? v : 0.f;
      __bf16 hi = (__bf16)v;
      __bf16 lo = (__bf16)(v - (float)hi);
      KmHi[idx] = hi; KmLo[idx] = lo;
      KTHi[a * 64 + l] = hi; KTLo[a * 64 + l] = lo;
    }
    if (tid < 64){ float v = ldin(AT, tid, isbf); atf[tid] = v > 0.f ? v : 0.f; }
    if (tid < 128){ bf_[tid] = ldin(bvec, tid, isbf); }
    // e-region: coalesced (consecutive lanes -> consecutive a)
    #pragma unroll
    for (int i = 0; i < 32; ++i){
      int idx = i * 256 + tid;          // 0..8191
      int y = idx >> 6, a = idx & 63;
      W2T[y * 4224 + 4096 + a] = (__bf16)ldin(e, a * 128 + y, isbf);
    }
    if (tid == 0){
      meta[0] = isbf ? 1 : 0;
      int mi = msin[0];
      if (mi <= 0 || mi > 1000000){
        float mf = ((const float*)msin)[0];
        mi = (mf > 0.f && mf < 1.0e6f) ? (int)mf : 50;
      }
      meta[1] = mi;
    }
  }
}

// split-bf16 GEMM quarter: 3 independent acc chains of depth 2
__device__ __forceinline__ float4v gemm3(const bf16x8* aH, const bf16x8* aL,
                                         const __bf16* s, int rdH){
  bf16x8 bH0 = *(const bf16x8*)(s + rdH);
  bf16x8 bL0 = *(const bf16x8*)(s + rdH + 8);
  bf16x8 bH1 = *(const bf16x8*)(s + rdH + 64);
  bf16x8 bL1 = *(const bf16x8*)(s + rdH + 72);
  float4v a0 = {0.f,0.f,0.f,0.f}, a1 = {0.f,0.f,0.f,0.f}, a2 = {0.f,0.f,0.f,0.f};
  a0 = __builtin_amdgcn_mfma_f32_16x16x32_bf16(aH[0], bH0, a0, 0, 0, 0);
  a1 = __builtin_amdgcn_mfma_f32_16x16x32_bf16(aH[0], bL0, a1, 0, 0, 0);
  a2 = __builtin_amdgcn_mfma_f32_16x16x32_bf16(aL[0], bH0, a2, 0, 0, 0);
  a0 = __builtin_amdgcn_mfma_f32_16x16x32_bf16(aH[1], bH1, a0, 0, 0, 0);
  a1 = __builtin_amdgcn_mfma_f32_16x16x32_bf16(aH[1], bL1, a1, 0, 0, 0);
  a2 = __builtin_amdgcn_mfma_f32_16x16x32_bf16(aL[1], bH1, a2, 0, 0, 0);
  return (a0 + a1) + a2;
}

__device__ __forceinline__ void wsplit(__bf16* s, int wH, float4v v){
  bf16x4 h, l;
  #pragma unroll
  for (int r = 0; r < 4; ++r){
    __bf16 hh = (__bf16)v[r];
    h[r] = hh; l[r] = (__bf16)(v[r] - (float)hh);
  }
  *(bf16x4*)(s + wH)     = h;
  *(bf16x4*)(s + wH + 8) = l;
}

// ---------------- main kernel: 16 rows per block, 4 waves ----------------
__global__ __launch_bounds__(256) void k_main(
    const float* ltf, const __bf16* KmHi, const __bf16* KmLo,
    const __bf16* KTHi, const __bf16* KTLo, const float* atf, const float* bf_,
    const __bf16* W2T, const int* meta, void* out)
{
  __shared__ __attribute__((aligned(16))) __bf16 sAF[16*SROW], sLF[16*SROW];
  __shared__ __attribute__((aligned(16))) __bf16 sLd[16*SROW], sAd[16*SROW];
  __shared__ float sErrA[4], sErrL[4];

  const int tid = threadIdx.x;
  const int wave = tid >> 6, lane = tid & 63;
  const int lr = lane & 15, q = lane >> 4;
  const int row0 = blockIdx.x * 16;
  const int dq = wave * 16 + q * 4;                      // dim-quad this lane owns
  const int rdH = lr * SROW + q * 16;                    // B-frag hi base (ks adds 64)
  const int wH  = lr * SROW + (dq >> 3) * 16 + (dq & 7); // C-quad hi writeback

  for (int i = tid; i < 16 * SROW; i += 256){
    sAF[i] = (__bf16)0.f; sLF[i] = (__bf16)0.f;
  }

  // invariant A-fragments
  bf16x8 aKmH[2], aKmL[2], aKTH[2], aKTL[2];
  #pragma unroll
  for (int ks = 0; ks < 2; ++ks){
    int o = (wave * 16 + lr) * 64 + ks * 32 + q * 8;
    aKmH[ks] = *(const bf16x8*)(KmHi + o);
    aKmL[ks] = *(const bf16x8*)(KmLo + o);
    aKTH[ks] = *(const bf16x8*)(KTHi + o);
    aKTL[ks] = *(const bf16x8*)(KTLo + o);
  }
  const float4v ltv = *(const float4v*)(ltf + (row0 + lr) * 64 + dq);
  const float4v atv = *(const float4v*)(atf + dq);
  const int isbf = meta[0];
  const int ms   = meta[1];

  float4v afold = {0.f,0.f,0.f,0.f}, lfold = {0.f,0.f,0.f,0.f};
  __syncthreads();

  for (int step = 0; step < ms; ++step){
    float4v s1 = gemm3(aKmH, aKmL, sAF, rdH);   // Km @ AF   (out m=l)
    float4v t2 = gemm3(aKTH, aKTL, sLF, rdH);   // KmT @ LF  (out m=a)
    float4v ld, ad;
    #pragma unroll
    for (int r = 0; r < 4; ++r){
      ld[r] = ltv[r] * frcp(s1[r] + 1.f);
      ad[r] = atv[r] * frcp(t2[r] + 1.f);
    }
    wsplit(sLd, wH, ld); wsplit(sAd, wH, ad);
    __syncthreads();
    float4v t3 = gemm3(aKTH, aKTL, sLd, rdH);   // KmT @ Ldi (out m=a)
    float4v t4 = gemm3(aKmH, aKmL, sAd, rdH);   // Km @ Adi  (out m=l)
    float eA = 0.f, eL = 0.f;
    float4v afn, lfn;
    #pragma unroll
    for (int r = 0; r < 4; ++r){
      afn[r] = atv[r] * frcp(t3[r] + 1.f);
      lfn[r] = ltv[r] * frcp(t4[r] + 1.f);
      eA = fmaxf(eA, fabsf(afn[r] - afold[r]) * frcp(afold[r] + 1e-5f));
      eL = fmaxf(eL, fabsf(lfn[r] - lfold[r]) * frcp(lfold[r] + 1e-5f));
    }
    afold = afn; lfold = lfn;
    wsplit(sAF, wH, afn); wsplit(sLF, wH, lfn);
    const bool chk = (step & 1) || (step == ms - 1);
    if (chk){
      #pragma unroll
      for (int off = 32; off >= 1; off >>= 1){
        eA = fmaxf(eA, __shfl_xor(eA, off));
        eL = fmaxf(eL, __shfl_xor(eL, off));
      }
      if (lane == 0){ sErrA[wave] = eA; sErrL[wave] = eL; }
    }
    __syncthreads();
    if (chk){
      float err = fmaxf(fmaxf(sErrA[0], sErrA[1]), fmaxf(sErrA[2], sErrA[3]))
                + fmaxf(fmaxf(sErrL[0], sErrL[1]), fmaxf(sErrL[2], sErrL[3]));
      if (err < 1e-3f) break;
    }
  }

  // final extra half-step pair -> AFf, LFf (hi only)
  {
    float4v s1 = gemm3(aKmH, aKmL, sAF, rdH);
    float4v t2 = gemm3(aKTH, aKTL, sLF, rdH);
    float4v ld, ad;
    #pragma unroll
    for (int r = 0; r < 4; ++r){
      ld[r] = ltv[r] * frcp(s1[r] + 1.f);
      ad[r] = atv[r] * frcp(t2[r] + 1.f);
    }
    wsplit(sLd, wH, ld); wsplit(sAd, wH, ad);
    __syncthreads();
    float4v t3 = gemm3(aKTH, aKTL, sLd, rdH);
    float4v t4 = gemm3(aKmH, aKmL, sAd, rdH);
    bf16x4 afh, lfh;
    #pragma unroll
    for (int r = 0; r < 4; ++r){
      afh[r] = (__bf16)(atv[r] * frcp(t3[r] + 1.f));
      lfh[r] = (__bf16)(ltv[r] * frcp(t4[r] + 1.f));
    }
    *(bf16x4*)(sAF + wH) = afh;
    *(bf16x4*)(sLF + wH) = lfh;
    __syncthreads();
  }

  // epilogue: y[16 x 128] = [D | AFf] (16 x 4160) @ W2T^T + bias  (no barriers)
  float4v acc0 = {0.f,0.f,0.f,0.f}, acc1 = {0.f,0.f,0.f,0.f};
  const int nBase = wave * 32;
  const __bf16* Wr0 = W2T + (nBase + lr) * 4224;
  const __bf16* Wr1 = Wr0 + 16 * 4224;
  for (int kc = 0; kc < 32; ++kc){
    #pragma unroll
    for (int kt = 0; kt < 4; ++kt){
      const int l = 2 * kc + (kt >> 1);
      const float lf = (float)sLF[lr * SROW + (l >> 3) * 16 + (l & 7)];
      bf16x8 af = *(const bf16x8*)(sAF + lr * SROW + ((kt & 1) * 4 + q) * 16);
      bf16x8 aD;
      #pragma unroll
      for (int j = 0; j < 8; ++j) aD[j] = (__bf16)(lf * (float)af[j]);
      const int kb = kc * 128 + kt * 32 + q * 8;
      bf16x8 b0 = *(const bf16x8*)(Wr0 + kb);
      bf16x8 b1 = *(const bf16x8*)(Wr1 + kb);
      acc0 = __builtin_amdgcn_mfma_f32_16x16x32_bf16(aD, b0, acc0, 0, 0, 0);
      acc1 = __builtin_amdgcn_mfma_f32_16x16x32_bf16(aD, b1, acc1, 0, 0, 0);
    }
  }
  #pragma unroll
  for (int kt = 0; kt < 2; ++kt){          // e-region (k = 4096..4159)
    bf16x8 aD = *(const bf16x8*)(sAF + lr * SROW + (kt * 4 + q) * 16);
    const int kb = 4096 + kt * 32 + q * 8;
    bf16x8 b0 = *(const bf16x8*)(Wr0 + kb);
    bf16x8 b1 = *(const bf16x8*)(Wr1 + kb);
    acc0 = __builtin_amdgcn_mfma_f32_16x16x32_bf16(aD, b0, acc0, 0, 0, 0);
    acc1 = __builtin_amdgcn_mfma_f32_16x16x32_bf16(aD, b1, acc1, 0, 0, 0);
  }

  const float b0v = bf_[nBase + lr];
  const float b1v = bf_[nBase + 16 + lr];
  const int obase = (row0 + q * 4) * 128;
  if (isbf){
    unsigned short* o = (unsigned short*)out;
    #pragma unroll
    for (int r = 0; r < 4; ++r){
      o[obase + r * 128 + nBase + lr]      = f2bf(acc0[r] + b0v);
      o[obase + r * 128 + nBase + 16 + lr] = f2bf(acc1[r] + b1v);
    }
  } else {
    float* o = (float*)out;
    #pragma unroll
    for (int r = 0; r < 4; ++r){
      o[obase + r * 128 + nBase + lr]      = acc0[r] + b0v;
      o[obase + r * 128 + nBase + 16 + lr] = acc1[r] + b1v;
    }
  }
}

extern "C" void kernel_launch(void* const* d_in, const int* in_sizes, int n_in,
                              void* d_out, int out_size, void* d_ws, size_t ws_size,
                              hipStream_t stream){
  char* ws = (char*)d_ws;
  int*    meta = (int*)ws;
  float*  atf  = (float*)(ws + 256);
  float*  bf_  = (float*)(ws + 512);
  __bf16* KmHi = (__bf16*)(ws + 1024);
  __bf16* KmLo = (__bf16*)(ws + 1024 + 8192);
  __bf16* KTHi = (__bf16*)(ws + 1024 + 16384);
  __bf16* KTLo = (__bf16*)(ws + 1024 + 24576);
  float*  ltf  = (float*)(ws + 33792);
  __bf16* W2T  = (__bf16*)(ws + 33792 + 1048576);

  k_prep<<<dim3(257), dim3(256), 0, stream>>>(
      d_in[0], d_in[1], d_in[2], d_in[3], d_in[4], d_in[5], (const int*)d_in[6],
      ltf, KmHi, KmLo, KTHi, KTLo, atf, bf_, W2T, meta);
  k_main<<<dim3(256), dim3(256), 0, stream>>>(
      ltf, KmHi, KmLo, KTHi, KTLo, atf, bf_, W2T, meta, d_out);
}